// Round 3
// baseline (175.743 us; speedup 1.0000x reference)
//
#include <hip/hip_runtime.h>
#include <math.h>

// Problem constants (reference: N=64, H=512, W=512, RATIO=2, ITERATIONS=1)
#define NIMG 64
#define HH 512
#define WW 512
#define SH 32                          // rows per wave strip
#define NSEG 8                         // 512/64 column segments (one per wave)
#define NSTRIP (HH / SH)               // 16
#define NBLOCKS (NIMG * NSTRIP)        // 1024 blocks x 512 threads = 8192 waves
#define INV_TOTAL (1.0f / 16777216.0f) // 1/(64*512*512), exact pow2

typedef unsigned long long u64;

#if defined(__has_builtin)
#  if __has_builtin(__builtin_amdgcn_inverse_ballot_w64)
#    define HAVE_INV_BALLOT 1
#  endif
#endif

// Wave-uniform scalar load (forces s_load via readfirstlane-uniform index).
__device__ __forceinline__ int uload(const int* __restrict__ p, int idx) {
    return p[__builtin_amdgcn_readfirstlane(idx)];
}

// Morphology on a binary mask with cv2 border semantics:
//   ero = !has_zero(valid 3x3), dil = has_one(valid 3x3)
//   border = dil & !ero = has_one & has_zero     (clipped cells feed neither)
// Per wave: 64-col segment, rolling 3-row window of wave-uniform 64-bit masks
// in SGPRs; all OR/shift morphology on the scalar pipe. No LDS, no barrier
// until the final reduction.
__global__ __launch_bounds__(512, 8) void border_loss_main(
    const float* __restrict__ x, const int* __restrict__ y,
    float* __restrict__ part, int atomic_mode)
{
    __shared__ float wsum[8];

    const int tid  = threadIdx.x;
    const int lane = tid & 63;
    const int s    = tid >> 6;           // segment 0..7 (one per wave)
    const int b    = blockIdx.x;
    const int n    = b >> 4;             // image
    const int R0   = (b & 15) * SH;      // first row of strip
    const int col0 = s << 6;
    const int ibase = n * (HH * WW) + col0;      // < 2^31, fits int
    const int*   __restrict__ yb = y + ibase;
    const float* __restrict__ xb = x + ibase;
    const bool hasL = (s > 0), hasR = (s < NSEG - 1);

    u64 bm_t, bz_t, bm_c, bz_c;          // (y>0) and (y==0) masks, rows r-1, r
    int lm_t, lz_t, rm_t, rz_t;          // boundary-col bools, row r-1
    int lm_c, lz_c, rm_c, rz_c;          // boundary-col bools, row r

    // ---- top halo row R0-1 (invalid rows contribute 0 to BOTH masks)
    if (R0 > 0) {
        const int o = (R0 - 1) * WW;
        int yv = yb[o + lane];
        bm_t = __ballot(yv > 0);
        bz_t = ~bm_t;
        if (hasL) { int v = uload(yb, o - 1);  lm_t = v > 0; lz_t = !lm_t; }
        else      { lm_t = 0; lz_t = 0; }
        if (hasR) { int v = uload(yb, o + 64); rm_t = v > 0; rz_t = !rm_t; }
        else      { rm_t = 0; rz_t = 0; }
    } else { bm_t = 0; bz_t = 0; lm_t = lz_t = rm_t = rz_t = 0; }

    // ---- row R0 (always valid)
    {
        const int o = R0 * WW;
        int yv = yb[o + lane];
        bm_c = __ballot(yv > 0);
        bz_c = ~bm_c;
        if (hasL) { int v = uload(yb, o - 1);  lm_c = v > 0; lz_c = !lm_c; }
        else      { lm_c = 0; lz_c = 0; }
        if (hasR) { int v = uload(yb, o + 64); rm_c = v > 0; rz_c = !rm_c; }
        else      { rm_c = 0; rz_c = 0; }
    }

    float acc = 0.0f;
    #pragma unroll 4
    for (int r = 0; r < SH; ++r) {
        const int gr = R0 + r;
        const float xf = xb[gr * WW + lane];

        // bottom row of the window (gr+1); may be past the image on last strip
        u64 bm_b = 0, bz_b = 0;
        int lm_b = 0, lz_b = 0, rm_b = 0, rz_b = 0;
        const int gb = gr + 1;
        if (gb < HH) {                   // wave-uniform branch
            const int o = gb * WW;
            int yv = yb[o + lane];
            bm_b = __ballot(yv > 0);
            bz_b = ~bm_b;
            if (hasL) { int v = uload(yb, o - 1);  lm_b = v > 0; lz_b = !lm_b; }
            if (hasR) { int v = uload(yb, o + 64); rm_b = v > 0; rz_b = !rm_b; }
        }

        // vertical OR (scalar pipe)
        const u64 vm = bm_t | bm_c | bm_b;
        const u64 vz = bz_t | bz_c | bz_b;
        // horizontal 3-window OR with boundary-column bits (scalar pipe)
        const u64 hm = vm | (vm << 1) | (vm >> 1)
                     | (u64)(unsigned)(lm_t | lm_c | lm_b)
                     | ((u64)(unsigned)(rm_t | rm_c | rm_b) << 63);
        const u64 hz = vz | (vz << 1) | (vz >> 1)
                     | (u64)(unsigned)(lz_t | lz_c | lz_b)
                     | ((u64)(unsigned)(rz_t | rz_c | rz_b) << 63);
        const u64 border = hm & hz;

        // per-lane loss: max(x,0) - x*m + ln(1 + e^{-|x|})  (hw exp/log)
        const float lg = __logf(1.0f + __expf(-fabsf(xf)));
#ifdef HAVE_INV_BALLOT
        const bool mbit = __builtin_amdgcn_inverse_ballot_w64(bm_c);
        const bool wbit = __builtin_amdgcn_inverse_ballot_w64(border);
#else
        const bool mbit = (bm_c   >> lane) & 1ull;
        const bool wbit = (border >> lane) & 1ull;
#endif
        const float loss = fmaxf(xf, 0.0f) - (mbit ? xf : 0.0f) + lg;
        acc = fmaf(loss, wbit ? 2.0f : 1.0f, acc);

        // roll the window
        bm_t = bm_c; bz_t = bz_c; bm_c = bm_b; bz_c = bz_b;
        lm_t = lm_c; lz_t = lz_c; lm_c = lm_b; lz_c = lz_b;
        rm_t = rm_c; rz_t = rz_c; rm_c = rm_b; rz_c = rz_b;
    }

    // ---- reduction: wave shuffle + tiny LDS across 8 waves
    #pragma unroll
    for (int off = 32; off > 0; off >>= 1)
        acc += __shfl_down(acc, off);
    if (lane == 0) wsum[s] = acc;
    __syncthreads();
    if (tid == 0) {
        float t = 0.0f;
        #pragma unroll
        for (int i = 0; i < 8; ++i) t += wsum[i];
        if (atomic_mode) atomicAdd(part, t * INV_TOTAL);
        else             part[blockIdx.x] = t;
    }
}

__global__ __launch_bounds__(256) void border_loss_reduce(
    const float* __restrict__ part, float* __restrict__ out)
{
    __shared__ float wsum[4];
    float t = 0.0f;
    for (int i = threadIdx.x; i < NBLOCKS; i += 256) t += part[i];
    #pragma unroll
    for (int off = 32; off > 0; off >>= 1)
        t += __shfl_down(t, off);
    if ((threadIdx.x & 63) == 0) wsum[threadIdx.x >> 6] = t;
    __syncthreads();
    if (threadIdx.x == 0)
        out[0] = (wsum[0] + wsum[1] + wsum[2] + wsum[3]) * INV_TOTAL;
}

__global__ void border_loss_zero(float* out) { out[0] = 0.0f; }

extern "C" void kernel_launch(void* const* d_in, const int* in_sizes, int n_in,
                              void* d_out, int out_size, void* d_ws, size_t ws_size,
                              hipStream_t stream)
{
    const float* x = (const float*)d_in[0];
    const int*   y = (const int*)d_in[1];
    float* out = (float*)d_out;

    if (ws_size >= (size_t)NBLOCKS * sizeof(float)) {
        // Deterministic two-stage reduction via workspace partials.
        float* part = (float*)d_ws;
        border_loss_main<<<NBLOCKS, 512, 0, stream>>>(x, y, part, 0);
        border_loss_reduce<<<1, 256, 0, stream>>>(part, out);
    } else {
        // Fallback: zero output then atomic accumulation.
        border_loss_zero<<<1, 1, 0, stream>>>(out);
        border_loss_main<<<NBLOCKS, 512, 0, stream>>>(x, y, out, 1);
    }
}